// Round 19
// baseline (131.581 us; speedup 1.0000x reference)
//
#include <hip/hip_runtime.h>
#include <cstdint>
#include <cstddef>

#define N1 4096
#define N2 16384
#define C1 256
#define C2 128
#define HH 256
#define K1 384
#define BQ 32768          // B*N2 total queries
#define KPAD 392          // LDS k-stride (bf16 elems): 16B-aligned, banks balanced
#define NCH 8             // NN point chunks (512 points each, 8KB LDS)

typedef float  f32x4  __attribute__((ext_vector_type(4)));
typedef __bf16 bf16x8 __attribute__((ext_vector_type(8)));
typedef __bf16 bf16x4 __attribute__((ext_vector_type(4)));

// Exact reference RN sequence for squared distance.
__device__ __forceinline__ float exact_dd(float ux, float uy, float uz,
                                          float su, float4 p) {
  float dot = __fadd_rn(__fadd_rn(__fmul_rn(ux, p.x), __fmul_rn(uy, p.y)),
                        __fmul_rn(uz, p.z));
  return __builtin_fmaf(dot, -2.0f, __fadd_rn(su, p.w));
}

// Load point j from p1 layout [3][N1] and build (x,y,z,|k|^2) with the exact
// RN sequence.
__device__ __forceinline__ float4 load_pt(const float* __restrict__ p1b,
                                          int j) {
  float x = p1b[j], y = p1b[N1 + j], z = p1b[2 * N1 + j];
  float sk = __fadd_rn(__fadd_rn(__fmul_rn(x, x), __fmul_rn(y, y)),
                       __fmul_rn(z, z));
  return make_float4(x, y, z, sk);
}

// Lexicographic (d, idx) insert == stable top-k semantics (ties -> lower idx).
#define LEXINS(da, db, dc, ia, ib, ic, dd, jj)                                 \
  {                                                                            \
    bool ca = ((dd) < (da)) || ((dd) == (da) && (jj) < (ia));                  \
    bool cb = ((dd) < (db)) || ((dd) == (db) && (jj) < (ib));                  \
    bool cc = ((dd) < (dc)) || ((dd) == (dc) && (jj) < (ic));                  \
    dc = cb ? (db) : (cc ? (dd) : (dc));                                       \
    ic = cb ? (ib) : (cc ? (jj) : (ic));                                       \
    db = ca ? (da) : (cb ? (dd) : (db));                                       \
    ib = ca ? (ia) : (cb ? (jj) : (ib));                                       \
    da = ca ? (dd) : (da);                                                     \
    ia = ca ? (jj) : (ia);                                                     \
  }

// Sorted top-4 maintain on float keys: 1 min + 3 med3.
#define KMIN4(K1_, K2_, K3_, K4_, x)                                           \
  {                                                                            \
    float n1 = fminf((K1_), (x));                                              \
    float n2 = __builtin_amdgcn_fmed3f((K1_), (x), (K2_));                     \
    float n3 = __builtin_amdgcn_fmed3f((K2_), (x), (K3_));                     \
    float n4 = __builtin_amdgcn_fmed3f((K3_), (x), (K4_));                     \
    K1_ = n1; K2_ = n2; K3_ = n3; K4_ = n4;                                    \
  }

// Per-point scalar distance + key + keyed insert (key low 12 bits = index).
#define POINTQ(ux, uy, uz, su, px, py, pz, pw, jj, Ka, Kb, Kc, Kd)             \
  {                                                                            \
    float dot_ = __fadd_rn(                                                    \
        __fadd_rn(__fmul_rn((ux), (px)), __fmul_rn((uy), (py))),               \
        __fmul_rn((uz), (pz)));                                                \
    float dd_ = __builtin_fmaf(dot_, -2.0f, __fadd_rn((su), (pw)));            \
    float xk_ = __uint_as_float((__float_as_uint(dd_) & 0xFFFFF000u) |         \
                                ((unsigned)(jj) & 0x00000FFFu));               \
    KMIN4(Ka, Kb, Kc, Kd, xk_);                                                \
  }

// ---------------------------------------------------------------------------
// k_front: one kernel, three independent block ranges (verbatim from the
// passing round-16/18 builds, ~54.5us with prep+transpose absorbed):
//   [0,384):    W1/W2 -> bf16; BN folded scale/shift.
//   [384,896):  transpose features1 [B,C1,N1] -> f1T [B,N1,C1].
//   [896,1408): keyed 3-NN partials, points staged from p1 (exact RN |k|^2).
// ---------------------------------------------------------------------------
__global__ __launch_bounds__(256) void k_front(
    const float* __restrict__ p1, const float* __restrict__ p2,
    const float* __restrict__ f1,
    const float* __restrict__ W1, const float* __restrict__ W2,
    const float* __restrict__ b1, const float* __restrict__ g1,
    const float* __restrict__ be1, const float* __restrict__ mm1,
    const float* __restrict__ vv1,
    const float* __restrict__ b2, const float* __restrict__ g2,
    const float* __restrict__ be2, const float* __restrict__ mm2,
    const float* __restrict__ vv2,
    __bf16* __restrict__ W1b, __bf16* __restrict__ W2b,
    float* __restrict__ scsh, float* __restrict__ f1T,
    float* __restrict__ keybuf) {
#pragma clang fp contract(off)
  __shared__ __align__(16) float smemf[64 * 65];   // 16,640B: tile / spts
  const int bx = blockIdx.x;
  const int t = threadIdx.x;

  if (bx < 384) {
    int idx = bx * 256 + t;
    if (idx < HH * K1) W1b[idx] = (__bf16)W1[idx];
    if (idx < HH * HH) W2b[idx] = (__bf16)W2[idx];
    if (idx < HH) {
      float sc = g1[idx] / sqrtf(vv1[idx] + 1e-3f);
      scsh[idx]          = sc;
      scsh[HH + idx]     = fmaf(b1[idx] - mm1[idx], sc, be1[idx]);
      float s2 = g2[idx] / sqrtf(vv2[idx] + 1e-3f);
      scsh[2 * HH + idx] = s2;
      scsh[3 * HH + idx] = fmaf(b2[idx] - mm2[idx], s2, be2[idx]);
    }
    return;
  }

  if (bx < 896) {
    float (*tile)[65] = (float(*)[65])smemf;
    const int bz = bx - 384;            // 0..511
    const int b = bz >> 8;
    const int rest = bz & 255;
    const int ct = rest >> 6;
    const int ntb = (rest & 63) << 6;
    const int ln = t & 63, g = t >> 6;

    const float* src = f1 + ((size_t)b * C1 + ct * 64) * N1 + ntb;
    for (int k = 0; k < 16; ++k) {
      int c = (k << 2) + g;
      tile[c][ln] = src[(size_t)c * N1 + ln];
    }
    __syncthreads();
    float* dst = f1T + ((size_t)b * N1 + ntb) * C1 + ct * 64;
    for (int k = 0; k < 16; ++k) {
      int nn = (k << 2) + g;
      dst[(size_t)nn * C1 + ln] = tile[ln][nn];
    }
    return;
  }

  // ---- NN scan ----
  float4* spts = (float4*)smemf;        // 8KB used
  const int bz = bx - 896;              // 0..511
  const int ch = bz & (NCH - 1);
  const int qt = bz >> 3;               // 0..63 (tiles of 512 queries)
  const int b  = qt >> 5;               // uniform per block
  const int nA = ((qt & 31) << 9) + t;  // query A
  const int nB = nA + 256;              // query B

  const float* p1b = p1 + (size_t)b * 3 * N1;
  {
    int j = ch * 512 + t;
    spts[t]       = load_pt(p1b, j);
    spts[t + 256] = load_pt(p1b, j + 256);
  }

  const float* p2b = p2 + (size_t)b * 3 * N2;
  float uxA = p2b[nA], uyA = p2b[N2 + nA], uzA = p2b[2 * N2 + nA];
  float suA = __fadd_rn(__fadd_rn(__fmul_rn(uxA, uxA), __fmul_rn(uyA, uyA)),
                        __fmul_rn(uzA, uzA));
  float uxB = p2b[nB], uyB = p2b[N2 + nB], uzB = p2b[2 * N2 + nB];
  float suB = __fadd_rn(__fadd_rn(__fmul_rn(uxB, uxB), __fmul_rn(uyB, uyB)),
                        __fmul_rn(uzB, uzB));
  __syncthreads();

  const int j0 = ch * 512;
  float KaA = 3.0e38f, KbA = 3.0e38f, KcA = 3.0e38f, KdA = 3.0e38f;
  float KaB = 3.0e38f, KbB = 3.0e38f, KcB = 3.0e38f, KdB = 3.0e38f;
#pragma unroll 4
  for (int k = 0; k < 256; ++k) {
    float4 p0 = spts[2 * k];
    float4 p1v = spts[2 * k + 1];
    int i0 = j0 + 2 * k;
    int i1 = j0 + 2 * k + 1;
    POINTQ(uxA, uyA, uzA, suA, p0.x, p0.y, p0.z, p0.w, i0, KaA, KbA, KcA, KdA);
    POINTQ(uxA, uyA, uzA, suA, p1v.x, p1v.y, p1v.z, p1v.w, i1, KaA, KbA, KcA, KdA);
    POINTQ(uxB, uyB, uzB, suB, p0.x, p0.y, p0.z, p0.w, i0, KaB, KbB, KcB, KdB);
    POINTQ(uxB, uyB, uzB, suB, p1v.x, p1v.y, p1v.z, p1v.w, i1, KaB, KbB, KcB, KdB);
  }

  int qA = b * N2 + nA;
  int qB = b * N2 + nB;
  keybuf[(ch * 4 + 0) * BQ + qA] = KaA;
  keybuf[(ch * 4 + 1) * BQ + qA] = KbA;
  keybuf[(ch * 4 + 2) * BQ + qA] = KcA;
  keybuf[(ch * 4 + 3) * BQ + qA] = KdA;
  keybuf[(ch * 4 + 0) * BQ + qB] = KaB;
  keybuf[(ch * 4 + 1) * BQ + qB] = KbB;
  keybuf[(ch * 4 + 2) * BQ + qB] = KcB;
  keybuf[(ch * 4 + 3) * BQ + qB] = KdB;
}

// ---------------------------------------------------------------------------
// k_fused: Phase A0 in-register merge (cheap candidate-only fallback — the
// r13/r14/r17 full-rescan was the catastrophe) + gather+interp -> bf16 LDS ->
// MFMA GEMM1 -> BN1+ReLU -> MFMA GEMM2 -> BN2+ReLU -> out.
// ROUND 19: 256 threads/block, 1024 blocks, 32-col tiles. r18 measured the
// gather as latency-bound at Occupancy 29% (512 blocks = 2/CU). Halving the
// tile halves LDS to 24.6KB -> 4 blocks/CU resident and doubles the block
// supply; per-wave output stays 2048 elems (64 rows x 32 cols, acc[4][2]).
// ---------------------------------------------------------------------------
__global__ __launch_bounds__(256) void k_fused(
    const float* __restrict__ f1T, const float* __restrict__ f2,
    const float* __restrict__ p2, const float* __restrict__ p1,
    const float* __restrict__ keybuf,
    const __bf16* __restrict__ W1b, const __bf16* __restrict__ W2b,
    const float* __restrict__ scsh, float* __restrict__ out) {
  __shared__ __bf16 sX[32 * KPAD];       // 24.6KB; x for GEMM1, then h
  const int t = threadIdx.x;
  const int bx = blockIdx.x;             // 1024 blocks
  const int b = bx >> 9;
  const int n0 = (bx & 511) << 5;        // 32-col tile base

  // ---- Phase A0: in-register 3-NN merge + weights (8 lanes per query) ----
  float w0, w1, w2;
  int i0, i1, i2;
  {
#pragma clang fp contract(off)
    const int sub = t & 7;
    const int n = n0 + (t >> 3);         // 32 queries per block
    const int gi = b * N2 + n;
    const float* p2b = p2 + (size_t)b * 3 * N2;
    float ux = p2b[n], uy = p2b[N2 + n], uz = p2b[2 * N2 + n];
    float su = __fadd_rn(__fadd_rn(__fmul_rn(ux, ux), __fmul_rn(uy, uy)),
                         __fmul_rn(uz, uz));

    float Ka = 3.0e38f, Kb = 3.0e38f, Kc = 3.0e38f, Kd = 3.0e38f;
#pragma unroll
    for (int m = 0; m < 4; ++m) {
      float x = keybuf[(sub * 4 + m) * BQ + gi];
      KMIN4(Ka, Kb, Kc, Kd, x);
    }
#pragma unroll
    for (int msk = 1; msk <= 4; msk <<= 1) {
      float ea = __shfl_xor(Ka, msk, 64), eb = __shfl_xor(Kb, msk, 64);
      float ec = __shfl_xor(Kc, msk, 64), ed = __shfl_xor(Kd, msk, 64);
      KMIN4(Ka, Kb, Kc, Kd, ea);
      KMIN4(Ka, Kb, Kc, Kd, eb);
      KMIN4(Ka, Kb, Kc, Kd, ec);
      KMIN4(Ka, Kb, Kc, Kd, ed);
    }
    bool flag = (__float_as_uint(Kc) >> 12) == (__float_as_uint(Kd) >> 12);

    const float* p1b = p1 + (size_t)b * 3 * N1;
    float da, db, dc;
    int ia, ib, ic;
    if (!flag) {
      ia = (int)(__float_as_uint(Ka) & 0xFFFu);
      ib = (int)(__float_as_uint(Kb) & 0xFFFu);
      ic = (int)(__float_as_uint(Kc) & 0xFFFu);
      da = exact_dd(ux, uy, uz, su, load_pt(p1b, ia));
      db = exact_dd(ux, uy, uz, su, load_pt(p1b, ib));
      dc = exact_dd(ux, uy, uz, su, load_pt(p1b, ic));
    } else {
      // cheap fallback: exact (d,idx) LEXINS over the 32 candidate keys
      da = 3.0e38f; db = 3.0e38f; dc = 3.0e38f;
      ia = 0x7fffffff; ib = 0x7fffffff; ic = 0x7fffffff;
#pragma unroll 4
      for (int i = 0; i < 4 * NCH; ++i) {
        float x = keybuf[i * BQ + gi];
        int jj = (int)(__float_as_uint(x) & 0xFFFu);
        float dd = exact_dd(ux, uy, uz, su, load_pt(p1b, jj));
        LEXINS(da, db, dc, ia, ib, ic, dd, jj);
      }
    }

    // exact reference weight arithmetic (all 8 lanes identically)
    float qa = fmaxf(da, 0.0f), qb = fmaxf(db, 0.0f), qc = fmaxf(dc, 0.0f);
    qa = fmaxf(__fmul_rn(qa, qa), 1e-10f);
    qb = fmaxf(__fmul_rn(qb, qb), 1e-10f);
    qc = fmaxf(__fmul_rn(qc, qc), 1e-10f);
    float va = __fdiv_rn(1.0f, qa);
    float vb = __fdiv_rn(1.0f, qb);
    float vc = __fdiv_rn(1.0f, qc);
    float s = __fadd_rn(__fadd_rn(va, vb), vc);
    w0 = __fdiv_rn(va, s);
    w1 = __fdiv_rn(vb, s);
    w2 = __fdiv_rn(vc, s);
    i0 = ia; i1 = ib; i2 = ic;
  }

  // ---- Phase A1: interp C1 channels; 8 threads/col x 8 float4 groups ----
  {
    const int qq = t & 7;
    const float4* r0 = (const float4*)(f1T + ((size_t)b * N1 + i0) * C1);
    const float4* r1 = (const float4*)(f1T + ((size_t)b * N1 + i1) * C1);
    const float4* r2 = (const float4*)(f1T + ((size_t)b * N1 + i2) * C1);
#pragma unroll 4
    for (int m = 0; m < 8; ++m) {
      int idx4 = (qq << 3) + m;          // 0..63
      float4 a = r0[idx4], c4 = r1[idx4], d4 = r2[idx4];
      bf16x4 v;
      v[0] = (__bf16)fmaf(w0, a.x, fmaf(w1, c4.x, w2 * d4.x));
      v[1] = (__bf16)fmaf(w0, a.y, fmaf(w1, c4.y, w2 * d4.y));
      v[2] = (__bf16)fmaf(w0, a.z, fmaf(w1, c4.z, w2 * d4.z));
      v[3] = (__bf16)fmaf(w0, a.w, fmaf(w1, c4.w, w2 * d4.w));
      *(bf16x4*)&sX[(t >> 3) * KPAD + (idx4 << 2)] = v;
    }
  }
  // ---- Phase A2: features2 channels (k = 256..383); 8 thr/col x 16 ch ----
  {
    const int col = t & 31, g = t >> 5;  // g = 0..7
    const float* f2b = f2 + (size_t)b * C2 * N2 + n0 + col;
#pragma unroll
    for (int m = 0; m < 4; ++m) {
      int c4 = (g << 4) + (m << 2);      // 0..124
      bf16x4 v;
      v[0] = (__bf16)f2b[(size_t)(c4 + 0) * N2];
      v[1] = (__bf16)f2b[(size_t)(c4 + 1) * N2];
      v[2] = (__bf16)f2b[(size_t)(c4 + 2) * N2];
      v[3] = (__bf16)f2b[(size_t)(c4 + 3) * N2];
      *(bf16x4*)&sX[col * KPAD + 256 + c4] = v;
    }
  }
  __syncthreads();

  const int l  = t & 63;
  const int wv = __builtin_amdgcn_readfirstlane(t >> 6);
  const int ob = wv << 6;                // 64 rows per wave (4 waves x 64)
  const int lm = l & 15, lg = l >> 4;

  f32x4 acc[4][2];
#pragma unroll
  for (int mt = 0; mt < 4; ++mt)
#pragma unroll
    for (int nt = 0; nt < 2; ++nt) acc[mt][nt] = (f32x4)0.0f;

  // ---- GEMM1: K = 384 (12 k-steps) ----
  for (int ks = 0; ks < 12; ++ks) {
    bf16x8 af[4], bfr[2];
#pragma unroll
    for (int mt = 0; mt < 4; ++mt)
      af[mt] = *(const bf16x8*)(W1b + (size_t)(ob + mt * 16 + lm) * K1 +
                                ks * 32 + lg * 8);
#pragma unroll
    for (int nt = 0; nt < 2; ++nt)
      bfr[nt] = *(const bf16x8*)&sX[(nt * 16 + lm) * KPAD + ks * 32 + lg * 8];
#pragma unroll
    for (int mt = 0; mt < 4; ++mt)
#pragma unroll
      for (int nt = 0; nt < 2; ++nt)
        acc[mt][nt] = __builtin_amdgcn_mfma_f32_16x16x32_bf16(
            af[mt], bfr[nt], acc[mt][nt], 0, 0, 0);
  }
  __syncthreads();

  // ---- BN1 + ReLU -> h (bf16) back into sX ----
#pragma unroll
  for (int mt = 0; mt < 4; ++mt) {
    int rb = ob + mt * 16 + lg * 4;
    float4 sc4 = *(const float4*)(scsh + rb);
    float4 sh4 = *(const float4*)(scsh + HH + rb);
#pragma unroll
    for (int nt = 0; nt < 2; ++nt) {
      int colc = nt * 16 + lm;
      bf16x4 v;
      v[0] = (__bf16)fmaxf(fmaf(acc[mt][nt][0], sc4.x, sh4.x), 0.0f);
      v[1] = (__bf16)fmaxf(fmaf(acc[mt][nt][1], sc4.y, sh4.y), 0.0f);
      v[2] = (__bf16)fmaxf(fmaf(acc[mt][nt][2], sc4.z, sh4.z), 0.0f);
      v[3] = (__bf16)fmaxf(fmaf(acc[mt][nt][3], sc4.w, sh4.w), 0.0f);
      *(bf16x4*)&sX[colc * KPAD + rb] = v;
    }
  }
  __syncthreads();

  // ---- GEMM2: K = 256 (8 k-steps) ----
  f32x4 ac2[4][2];
#pragma unroll
  for (int mt = 0; mt < 4; ++mt)
#pragma unroll
    for (int nt = 0; nt < 2; ++nt) ac2[mt][nt] = (f32x4)0.0f;
  for (int ks = 0; ks < 8; ++ks) {
    bf16x8 af[4], bfr[2];
#pragma unroll
    for (int mt = 0; mt < 4; ++mt)
      af[mt] = *(const bf16x8*)(W2b + (size_t)(ob + mt * 16 + lm) * HH +
                                ks * 32 + lg * 8);
#pragma unroll
    for (int nt = 0; nt < 2; ++nt)
      bfr[nt] = *(const bf16x8*)&sX[(nt * 16 + lm) * KPAD + ks * 32 + lg * 8];
#pragma unroll
    for (int mt = 0; mt < 4; ++mt)
#pragma unroll
      for (int nt = 0; nt < 2; ++nt)
        ac2[mt][nt] = __builtin_amdgcn_mfma_f32_16x16x32_bf16(
            af[mt], bfr[nt], ac2[mt][nt], 0, 0, 0);
  }

  // ---- BN2 + ReLU -> out (fp32) ----
  float* outb = out + (size_t)b * HH * N2 + n0;
#pragma unroll
  for (int mt = 0; mt < 4; ++mt) {
    int rb = ob + mt * 16 + lg * 4;
    float4 sc4 = *(const float4*)(scsh + 2 * HH + rb);
    float4 sh4 = *(const float4*)(scsh + 3 * HH + rb);
#pragma unroll
    for (int nt = 0; nt < 2; ++nt) {
      int colc = nt * 16 + lm;
      outb[(size_t)(rb + 0) * N2 + colc] =
          fmaxf(fmaf(ac2[mt][nt][0], sc4.x, sh4.x), 0.0f);
      outb[(size_t)(rb + 1) * N2 + colc] =
          fmaxf(fmaf(ac2[mt][nt][1], sc4.y, sh4.y), 0.0f);
      outb[(size_t)(rb + 2) * N2 + colc] =
          fmaxf(fmaf(ac2[mt][nt][2], sc4.z, sh4.z), 0.0f);
      outb[(size_t)(rb + 3) * N2 + colc] =
          fmaxf(fmaf(ac2[mt][nt][3], sc4.w, sh4.w), 0.0f);
    }
  }
}

// ---------------------------------------------------------------------------
extern "C" void kernel_launch(void* const* d_in, const int* in_sizes, int n_in,
                              void* d_out, int out_size, void* d_ws, size_t ws_size,
                              hipStream_t stream) {
  const float* p1  = (const float*)d_in[0];
  const float* p2  = (const float*)d_in[1];
  const float* f1  = (const float*)d_in[2];
  const float* f2  = (const float*)d_in[3];
  const float* W1  = (const float*)d_in[4];
  const float* bb1 = (const float*)d_in[5];
  const float* g1  = (const float*)d_in[6];
  const float* be1 = (const float*)d_in[7];
  const float* mm1 = (const float*)d_in[8];
  const float* vv1 = (const float*)d_in[9];
  const float* W2  = (const float*)d_in[10];
  const float* bb2 = (const float*)d_in[11];
  const float* g2  = (const float*)d_in[12];
  const float* be2 = (const float*)d_in[13];
  const float* mm2 = (const float*)d_in[14];
  const float* vv2 = (const float*)d_in[15];
  float* out = (float*)d_out;

  // ws layout (~12.9 MB, no aliasing — f1T and keybuf both live across
  // k_front..k_fused).
  char* ws = (char*)d_ws;
  float*  f1T    = (float*)(ws);                 // 8,388,608 B
  float*  keybuf = (float*)(ws + 8388608);       // 4,194,304 B (32 planes)
  __bf16* W1b    = (__bf16*)(ws + 12582912);     //   196,608 B
  __bf16* W2b    = (__bf16*)(ws + 12779520);     //   131,072 B
  float*  scsh   = (float*)(ws + 12910592);      //     4,096 B

  k_front<<<1408, 256, 0, stream>>>(p1, p2, f1, W1, W2,
                                    bb1, g1, be1, mm1, vv1,
                                    bb2, g2, be2, mm2, vv2,
                                    W1b, W2b, scsh, f1T, keybuf);
  k_fused<<<1024, 256, 0, stream>>>(f1T, f2, p2, p1, keybuf,
                                    W1b, W2b, scsh, out);
}

// Round 20
// 99.297 us; speedup vs baseline: 1.3251x; 1.3251x over previous
//
#include <hip/hip_runtime.h>
#include <cstdint>
#include <cstddef>

#define N1 4096
#define N2 16384
#define C1 256
#define C2 128
#define HH 256
#define K1 384
#define BQ 32768          // B*N2 total queries
#define KPAD 392          // LDS k-stride (bf16 elems): 16B-aligned, banks balanced
#define NCH 8             // NN point chunks (512 points each, 8KB LDS)

typedef float  f32x4  __attribute__((ext_vector_type(4)));
typedef __bf16 bf16x8 __attribute__((ext_vector_type(8)));
typedef __bf16 bf16x4 __attribute__((ext_vector_type(4)));

// Exact reference RN sequence for squared distance.
__device__ __forceinline__ float exact_dd(float ux, float uy, float uz,
                                          float su, float4 p) {
  float dot = __fadd_rn(__fadd_rn(__fmul_rn(ux, p.x), __fmul_rn(uy, p.y)),
                        __fmul_rn(uz, p.z));
  return __builtin_fmaf(dot, -2.0f, __fadd_rn(su, p.w));
}

// Load point j from p1 layout [3][N1] and build (x,y,z,|k|^2) with the exact
// RN sequence.
__device__ __forceinline__ float4 load_pt(const float* __restrict__ p1b,
                                          int j) {
  float x = p1b[j], y = p1b[N1 + j], z = p1b[2 * N1 + j];
  float sk = __fadd_rn(__fadd_rn(__fmul_rn(x, x), __fmul_rn(y, y)),
                       __fmul_rn(z, z));
  return make_float4(x, y, z, sk);
}

// Lexicographic (d, idx) insert == stable top-k semantics (ties -> lower idx).
#define LEXINS(da, db, dc, ia, ib, ic, dd, jj)                                 \
  {                                                                            \
    bool ca = ((dd) < (da)) || ((dd) == (da) && (jj) < (ia));                  \
    bool cb = ((dd) < (db)) || ((dd) == (db) && (jj) < (ib));                  \
    bool cc = ((dd) < (dc)) || ((dd) == (dc) && (jj) < (ic));                  \
    dc = cb ? (db) : (cc ? (dd) : (dc));                                       \
    ic = cb ? (ib) : (cc ? (jj) : (ic));                                       \
    db = ca ? (da) : (cb ? (dd) : (db));                                       \
    ib = ca ? (ia) : (cb ? (jj) : (ib));                                       \
    da = ca ? (dd) : (da);                                                     \
    ia = ca ? (jj) : (ia);                                                     \
  }

// Sorted top-4 maintain on float keys: 1 min + 3 med3.
#define KMIN4(K1_, K2_, K3_, K4_, x)                                           \
  {                                                                            \
    float n1 = fminf((K1_), (x));                                              \
    float n2 = __builtin_amdgcn_fmed3f((K1_), (x), (K2_));                     \
    float n3 = __builtin_amdgcn_fmed3f((K2_), (x), (K3_));                     \
    float n4 = __builtin_amdgcn_fmed3f((K3_), (x), (K4_));                     \
    K1_ = n1; K2_ = n2; K3_ = n3; K4_ = n4;                                    \
  }

// Per-point scalar distance + key + keyed insert (key low 12 bits = index).
#define POINTQ(ux, uy, uz, su, px, py, pz, pw, jj, Ka, Kb, Kc, Kd)             \
  {                                                                            \
    float dot_ = __fadd_rn(                                                    \
        __fadd_rn(__fmul_rn((ux), (px)), __fmul_rn((uy), (py))),               \
        __fmul_rn((uz), (pz)));                                                \
    float dd_ = __builtin_fmaf(dot_, -2.0f, __fadd_rn((su), (pw)));            \
    float xk_ = __uint_as_float((__float_as_uint(dd_) & 0xFFFFF000u) |         \
                                ((unsigned)(jj) & 0x00000FFFu));               \
    KMIN4(Ka, Kb, Kc, Kd, xk_);                                                \
  }

// ---------------------------------------------------------------------------
// k_front: one kernel, three independent block ranges (r16/r18 proven):
//   [0,384):    W1/W2 -> bf16; BN folded scale/shift.
//   [384,896):  transpose features1 [B,C1,N1] -> f1Tb [B,N1,C1] in BF16
//               (halves gather + write traffic; values feed bf16 MFMA anyway).
//   [896,1408): keyed 3-NN partials, points staged from p1 (exact RN |k|^2).
// ---------------------------------------------------------------------------
__global__ __launch_bounds__(256) void k_front(
    const float* __restrict__ p1, const float* __restrict__ p2,
    const float* __restrict__ f1,
    const float* __restrict__ W1, const float* __restrict__ W2,
    const float* __restrict__ b1, const float* __restrict__ g1,
    const float* __restrict__ be1, const float* __restrict__ mm1,
    const float* __restrict__ vv1,
    const float* __restrict__ b2, const float* __restrict__ g2,
    const float* __restrict__ be2, const float* __restrict__ mm2,
    const float* __restrict__ vv2,
    __bf16* __restrict__ W1b, __bf16* __restrict__ W2b,
    float* __restrict__ scsh, __bf16* __restrict__ f1Tb,
    float* __restrict__ keybuf) {
#pragma clang fp contract(off)
  __shared__ __align__(16) float smemf[64 * 65];   // 16,640B: tile / spts
  const int bx = blockIdx.x;
  const int t = threadIdx.x;

  if (bx < 384) {
    int idx = bx * 256 + t;
    if (idx < HH * K1) W1b[idx] = (__bf16)W1[idx];
    if (idx < HH * HH) W2b[idx] = (__bf16)W2[idx];
    if (idx < HH) {
      float sc = g1[idx] / sqrtf(vv1[idx] + 1e-3f);
      scsh[idx]          = sc;
      scsh[HH + idx]     = fmaf(b1[idx] - mm1[idx], sc, be1[idx]);
      float s2 = g2[idx] / sqrtf(vv2[idx] + 1e-3f);
      scsh[2 * HH + idx] = s2;
      scsh[3 * HH + idx] = fmaf(b2[idx] - mm2[idx], s2, be2[idx]);
    }
    return;
  }

  if (bx < 896) {
    float (*tile)[65] = (float(*)[65])smemf;
    const int bz = bx - 384;            // 0..511
    const int b = bz >> 8;
    const int rest = bz & 255;
    const int ct = rest >> 6;
    const int ntb = (rest & 63) << 6;
    const int ln = t & 63, g = t >> 6;

    const float* src = f1 + ((size_t)b * C1 + ct * 64) * N1 + ntb;
    for (int k = 0; k < 16; ++k) {
      int c = (k << 2) + g;
      tile[c][ln] = src[(size_t)c * N1 + ln];
    }
    __syncthreads();
    __bf16* dst = f1Tb + ((size_t)b * N1 + ntb) * C1 + ct * 64;
    for (int k = 0; k < 16; ++k) {
      int nn = (k << 2) + g;
      dst[(size_t)nn * C1 + ln] = (__bf16)tile[ln][nn];
    }
    return;
  }

  // ---- NN scan ----
  float4* spts = (float4*)smemf;        // 8KB used
  const int bz = bx - 896;              // 0..511
  const int ch = bz & (NCH - 1);
  const int qt = bz >> 3;               // 0..63 (tiles of 512 queries)
  const int b  = qt >> 5;               // uniform per block
  const int nA = ((qt & 31) << 9) + t;  // query A
  const int nB = nA + 256;              // query B

  const float* p1b = p1 + (size_t)b * 3 * N1;
  {
    int j = ch * 512 + t;
    spts[t]       = load_pt(p1b, j);
    spts[t + 256] = load_pt(p1b, j + 256);
  }

  const float* p2b = p2 + (size_t)b * 3 * N2;
  float uxA = p2b[nA], uyA = p2b[N2 + nA], uzA = p2b[2 * N2 + nA];
  float suA = __fadd_rn(__fadd_rn(__fmul_rn(uxA, uxA), __fmul_rn(uyA, uyA)),
                        __fmul_rn(uzA, uzA));
  float uxB = p2b[nB], uyB = p2b[N2 + nB], uzB = p2b[2 * N2 + nB];
  float suB = __fadd_rn(__fadd_rn(__fmul_rn(uxB, uxB), __fmul_rn(uyB, uyB)),
                        __fmul_rn(uzB, uzB));
  __syncthreads();

  const int j0 = ch * 512;
  float KaA = 3.0e38f, KbA = 3.0e38f, KcA = 3.0e38f, KdA = 3.0e38f;
  float KaB = 3.0e38f, KbB = 3.0e38f, KcB = 3.0e38f, KdB = 3.0e38f;
#pragma unroll 4
  for (int k = 0; k < 256; ++k) {
    float4 p0 = spts[2 * k];
    float4 p1v = spts[2 * k + 1];
    int i0 = j0 + 2 * k;
    int i1 = j0 + 2 * k + 1;
    POINTQ(uxA, uyA, uzA, suA, p0.x, p0.y, p0.z, p0.w, i0, KaA, KbA, KcA, KdA);
    POINTQ(uxA, uyA, uzA, suA, p1v.x, p1v.y, p1v.z, p1v.w, i1, KaA, KbA, KcA, KdA);
    POINTQ(uxB, uyB, uzB, suB, p0.x, p0.y, p0.z, p0.w, i0, KaB, KbB, KcB, KdB);
    POINTQ(uxB, uyB, uzB, suB, p1v.x, p1v.y, p1v.z, p1v.w, i1, KaB, KbB, KcB, KdB);
  }

  int qA = b * N2 + nA;
  int qB = b * N2 + nB;
  keybuf[(ch * 4 + 0) * BQ + qA] = KaA;
  keybuf[(ch * 4 + 1) * BQ + qA] = KbA;
  keybuf[(ch * 4 + 2) * BQ + qA] = KcA;
  keybuf[(ch * 4 + 3) * BQ + qA] = KdA;
  keybuf[(ch * 4 + 0) * BQ + qB] = KaB;
  keybuf[(ch * 4 + 1) * BQ + qB] = KbB;
  keybuf[(ch * 4 + 2) * BQ + qB] = KcB;
  keybuf[(ch * 4 + 3) * BQ + qB] = KdB;
}

// ---------------------------------------------------------------------------
// k_fused: Phase A0 in-register merge (cheap candidate-only fallback) +
// bf16-row gather+interp -> bf16 LDS -> MFMA GEMM1 -> BN1+ReLU -> MFMA
// GEMM2 -> BN2+ReLU -> out. Structure verbatim from the passing r18 build
// (512 threads, 64-col tile); only the gather source is now bf16 (12 16B
// loads/thread instead of 24 — half the latency-bound traffic).
// ---------------------------------------------------------------------------
__global__ __launch_bounds__(512) void k_fused(
    const __bf16* __restrict__ f1Tb, const float* __restrict__ f2,
    const float* __restrict__ p2, const float* __restrict__ p1,
    const float* __restrict__ keybuf,
    const __bf16* __restrict__ W1b, const __bf16* __restrict__ W2b,
    const float* __restrict__ scsh, float* __restrict__ out) {
  __shared__ __bf16 sX[64 * KPAD];       // 49KB; x for GEMM1, then h
  const int t = threadIdx.x;
  const int bx = blockIdx.x;
  const int b = bx >> 8;
  const int n0 = (bx & 255) << 6;

  // ---- Phase A0: in-register 3-NN merge + weights (8 lanes per query) ----
  float w0, w1, w2;
  int i0, i1, i2;
  {
#pragma clang fp contract(off)
    const int sub = t & 7;
    const int n = n0 + (t >> 3);
    const int gi = b * N2 + n;
    const float* p2b = p2 + (size_t)b * 3 * N2;
    float ux = p2b[n], uy = p2b[N2 + n], uz = p2b[2 * N2 + n];
    float su = __fadd_rn(__fadd_rn(__fmul_rn(ux, ux), __fmul_rn(uy, uy)),
                         __fmul_rn(uz, uz));

    float Ka = 3.0e38f, Kb = 3.0e38f, Kc = 3.0e38f, Kd = 3.0e38f;
#pragma unroll
    for (int m = 0; m < 4; ++m) {
      float x = keybuf[(sub * 4 + m) * BQ + gi];
      KMIN4(Ka, Kb, Kc, Kd, x);
    }
#pragma unroll
    for (int msk = 1; msk <= 4; msk <<= 1) {
      float ea = __shfl_xor(Ka, msk, 64), eb = __shfl_xor(Kb, msk, 64);
      float ec = __shfl_xor(Kc, msk, 64), ed = __shfl_xor(Kd, msk, 64);
      KMIN4(Ka, Kb, Kc, Kd, ea);
      KMIN4(Ka, Kb, Kc, Kd, eb);
      KMIN4(Ka, Kb, Kc, Kd, ec);
      KMIN4(Ka, Kb, Kc, Kd, ed);
    }
    bool flag = (__float_as_uint(Kc) >> 12) == (__float_as_uint(Kd) >> 12);

    const float* p1b = p1 + (size_t)b * 3 * N1;
    float da, db, dc;
    int ia, ib, ic;
    if (!flag) {
      ia = (int)(__float_as_uint(Ka) & 0xFFFu);
      ib = (int)(__float_as_uint(Kb) & 0xFFFu);
      ic = (int)(__float_as_uint(Kc) & 0xFFFu);
      da = exact_dd(ux, uy, uz, su, load_pt(p1b, ia));
      db = exact_dd(ux, uy, uz, su, load_pt(p1b, ib));
      dc = exact_dd(ux, uy, uz, su, load_pt(p1b, ic));
    } else {
      // cheap fallback: exact (d,idx) LEXINS over the 32 candidate keys
      da = 3.0e38f; db = 3.0e38f; dc = 3.0e38f;
      ia = 0x7fffffff; ib = 0x7fffffff; ic = 0x7fffffff;
#pragma unroll 4
      for (int i = 0; i < 4 * NCH; ++i) {
        float x = keybuf[i * BQ + gi];
        int jj = (int)(__float_as_uint(x) & 0xFFFu);
        float dd = exact_dd(ux, uy, uz, su, load_pt(p1b, jj));
        LEXINS(da, db, dc, ia, ib, ic, dd, jj);
      }
    }

    // exact reference weight arithmetic (all 8 lanes identically)
    float qa = fmaxf(da, 0.0f), qb = fmaxf(db, 0.0f), qc = fmaxf(dc, 0.0f);
    qa = fmaxf(__fmul_rn(qa, qa), 1e-10f);
    qb = fmaxf(__fmul_rn(qb, qb), 1e-10f);
    qc = fmaxf(__fmul_rn(qc, qc), 1e-10f);
    float va = __fdiv_rn(1.0f, qa);
    float vb = __fdiv_rn(1.0f, qb);
    float vc = __fdiv_rn(1.0f, qc);
    float s = __fadd_rn(__fadd_rn(va, vb), vc);
    w0 = __fdiv_rn(va, s);
    w1 = __fdiv_rn(vb, s);
    w2 = __fdiv_rn(vc, s);
    i0 = ia; i1 = ib; i2 = ic;
  }

  // ---- Phase A1: interp C1 channels from bf16 rows; 8 thr/col x 4 chunks --
  {
    const int qq = t & 7;
    const __bf16* r0 = f1Tb + ((size_t)b * N1 + i0) * C1;
    const __bf16* r1 = f1Tb + ((size_t)b * N1 + i1) * C1;
    const __bf16* r2 = f1Tb + ((size_t)b * N1 + i2) * C1;
#pragma unroll
    for (int m = 0; m < 4; ++m) {
      int c8 = ((qq << 2) + m) << 3;     // element base 0..248
      bf16x8 a = *(const bf16x8*)(r0 + c8);
      bf16x8 c4 = *(const bf16x8*)(r1 + c8);
      bf16x8 d4 = *(const bf16x8*)(r2 + c8);
      bf16x8 v;
#pragma unroll
      for (int e = 0; e < 8; ++e)
        v[e] = (__bf16)fmaf(w0, (float)a[e],
                            fmaf(w1, (float)c4[e], w2 * (float)d4[e]));
      *(bf16x8*)&sX[(t >> 3) * KPAD + c8] = v;
    }
  }
  // ---- Phase A2: features2 channels (k = 256..383) ----
  {
    const int col = t & 63, g = t >> 6;
    const float* f2b = f2 + (size_t)b * C2 * N2 + n0 + col;
#pragma unroll
    for (int m = 0; m < 4; ++m) {
      int c4 = (g << 4) + (m << 2);
      bf16x4 v;
      v[0] = (__bf16)f2b[(size_t)(c4 + 0) * N2];
      v[1] = (__bf16)f2b[(size_t)(c4 + 1) * N2];
      v[2] = (__bf16)f2b[(size_t)(c4 + 2) * N2];
      v[3] = (__bf16)f2b[(size_t)(c4 + 3) * N2];
      *(bf16x4*)&sX[col * KPAD + 256 + c4] = v;
    }
  }
  __syncthreads();

  const int l  = t & 63;
  const int wv = __builtin_amdgcn_readfirstlane(t >> 6);
  const int ob = wv << 5;                // 32 rows per wave
  const int lm = l & 15, lg = l >> 4;

  f32x4 acc[2][4];
#pragma unroll
  for (int mt = 0; mt < 2; ++mt)
#pragma unroll
    for (int nt = 0; nt < 4; ++nt) acc[mt][nt] = (f32x4)0.0f;

  // ---- GEMM1: K = 384 (12 k-steps) ----
  for (int ks = 0; ks < 12; ++ks) {
    bf16x8 af[2], bfr[4];
#pragma unroll
    for (int mt = 0; mt < 2; ++mt)
      af[mt] = *(const bf16x8*)(W1b + (size_t)(ob + mt * 16 + lm) * K1 +
                                ks * 32 + lg * 8);
#pragma unroll
    for (int nt = 0; nt < 4; ++nt)
      bfr[nt] = *(const bf16x8*)&sX[(nt * 16 + lm) * KPAD + ks * 32 + lg * 8];
#pragma unroll
    for (int mt = 0; mt < 2; ++mt)
#pragma unroll
      for (int nt = 0; nt < 4; ++nt)
        acc[mt][nt] = __builtin_amdgcn_mfma_f32_16x16x32_bf16(
            af[mt], bfr[nt], acc[mt][nt], 0, 0, 0);
  }
  __syncthreads();

  // ---- BN1 + ReLU -> h (bf16) back into sX ----
#pragma unroll
  for (int mt = 0; mt < 2; ++mt) {
    int rb = ob + mt * 16 + lg * 4;
    float4 sc4 = *(const float4*)(scsh + rb);
    float4 sh4 = *(const float4*)(scsh + HH + rb);
#pragma unroll
    for (int nt = 0; nt < 4; ++nt) {
      int colc = nt * 16 + lm;
      bf16x4 v;
      v[0] = (__bf16)fmaxf(fmaf(acc[mt][nt][0], sc4.x, sh4.x), 0.0f);
      v[1] = (__bf16)fmaxf(fmaf(acc[mt][nt][1], sc4.y, sh4.y), 0.0f);
      v[2] = (__bf16)fmaxf(fmaf(acc[mt][nt][2], sc4.z, sh4.z), 0.0f);
      v[3] = (__bf16)fmaxf(fmaf(acc[mt][nt][3], sc4.w, sh4.w), 0.0f);
      *(bf16x4*)&sX[colc * KPAD + rb] = v;
    }
  }
  __syncthreads();

  // ---- GEMM2: K = 256 (8 k-steps) ----
  f32x4 ac2[2][4];
#pragma unroll
  for (int mt = 0; mt < 2; ++mt)
#pragma unroll
    for (int nt = 0; nt < 4; ++nt) ac2[mt][nt] = (f32x4)0.0f;
  for (int ks = 0; ks < 8; ++ks) {
    bf16x8 af[2], bfr[4];
#pragma unroll
    for (int mt = 0; mt < 2; ++mt)
      af[mt] = *(const bf16x8*)(W2b + (size_t)(ob + mt * 16 + lm) * HH +
                                ks * 32 + lg * 8);
#pragma unroll
    for (int nt = 0; nt < 4; ++nt)
      bfr[nt] = *(const bf16x8*)&sX[(nt * 16 + lm) * KPAD + ks * 32 + lg * 8];
#pragma unroll
    for (int mt = 0; mt < 2; ++mt)
#pragma unroll
      for (int nt = 0; nt < 4; ++nt)
        ac2[mt][nt] = __builtin_amdgcn_mfma_f32_16x16x32_bf16(
            af[mt], bfr[nt], ac2[mt][nt], 0, 0, 0);
  }

  // ---- BN2 + ReLU -> out (fp32) ----
  float* outb = out + (size_t)b * HH * N2 + n0;
#pragma unroll
  for (int mt = 0; mt < 2; ++mt) {
    int rb = ob + mt * 16 + lg * 4;
    float4 sc4 = *(const float4*)(scsh + 2 * HH + rb);
    float4 sh4 = *(const float4*)(scsh + 3 * HH + rb);
#pragma unroll
    for (int nt = 0; nt < 4; ++nt) {
      int colc = nt * 16 + lm;
      outb[(size_t)(rb + 0) * N2 + colc] =
          fmaxf(fmaf(ac2[mt][nt][0], sc4.x, sh4.x), 0.0f);
      outb[(size_t)(rb + 1) * N2 + colc] =
          fmaxf(fmaf(ac2[mt][nt][1], sc4.y, sh4.y), 0.0f);
      outb[(size_t)(rb + 2) * N2 + colc] =
          fmaxf(fmaf(ac2[mt][nt][2], sc4.z, sh4.z), 0.0f);
      outb[(size_t)(rb + 3) * N2 + colc] =
          fmaxf(fmaf(ac2[mt][nt][3], sc4.w, sh4.w), 0.0f);
    }
  }
}

// ---------------------------------------------------------------------------
extern "C" void kernel_launch(void* const* d_in, const int* in_sizes, int n_in,
                              void* d_out, int out_size, void* d_ws, size_t ws_size,
                              hipStream_t stream) {
  const float* p1  = (const float*)d_in[0];
  const float* p2  = (const float*)d_in[1];
  const float* f1  = (const float*)d_in[2];
  const float* f2  = (const float*)d_in[3];
  const float* W1  = (const float*)d_in[4];
  const float* bb1 = (const float*)d_in[5];
  const float* g1  = (const float*)d_in[6];
  const float* be1 = (const float*)d_in[7];
  const float* mm1 = (const float*)d_in[8];
  const float* vv1 = (const float*)d_in[9];
  const float* W2  = (const float*)d_in[10];
  const float* bb2 = (const float*)d_in[11];
  const float* g2  = (const float*)d_in[12];
  const float* be2 = (const float*)d_in[13];
  const float* mm2 = (const float*)d_in[14];
  const float* vv2 = (const float*)d_in[15];
  float* out = (float*)d_out;

  // ws layout (~8.7 MB, no aliasing — f1Tb now bf16 = 4MB).
  char* ws = (char*)d_ws;
  __bf16* f1Tb   = (__bf16*)(ws);                // 4,194,304 B
  float*  keybuf = (float*)(ws + 4194304);       // 4,194,304 B (32 planes)
  __bf16* W1b    = (__bf16*)(ws + 8388608);      //   196,608 B
  __bf16* W2b    = (__bf16*)(ws + 8585216);      //   131,072 B
  float*  scsh   = (float*)(ws + 8716288);       //     4,096 B

  k_front<<<1408, 256, 0, stream>>>(p1, p2, f1, W1, W2,
                                    bb1, g1, be1, mm1, vv1,
                                    bb2, g2, be2, mm2, vv2,
                                    W1b, W2b, scsh, f1Tb, keybuf);
  k_fused<<<512, 512, 0, stream>>>(f1Tb, f2, p2, p1, keybuf,
                                   W1b, W2b, scsh, out);
}

// Round 21
// 97.821 us; speedup vs baseline: 1.3451x; 1.0151x over previous
//
#include <hip/hip_runtime.h>
#include <cstdint>
#include <cstddef>

#define N1 4096
#define N2 16384
#define C1 256
#define C2 128
#define HH 256
#define K1 384
#define BQ 32768          // B*N2 total queries
#define KPAD 392          // LDS k-stride (bf16 elems): 16B-aligned, banks balanced
#define NCH 8             // NN point chunks (512 points each, 8KB LDS)

typedef float  f32x4  __attribute__((ext_vector_type(4)));
typedef __bf16 bf16x8 __attribute__((ext_vector_type(8)));
typedef __bf16 bf16x4 __attribute__((ext_vector_type(4)));

// Exact reference RN sequence for squared distance.
__device__ __forceinline__ float exact_dd(float ux, float uy, float uz,
                                          float su, float4 p) {
  float dot = __fadd_rn(__fadd_rn(__fmul_rn(ux, p.x), __fmul_rn(uy, p.y)),
                        __fmul_rn(uz, p.z));
  return __builtin_fmaf(dot, -2.0f, __fadd_rn(su, p.w));
}

// Load point j from p1 layout [3][N1] and build (x,y,z,|k|^2) with the exact
// RN sequence.
__device__ __forceinline__ float4 load_pt(const float* __restrict__ p1b,
                                          int j) {
  float x = p1b[j], y = p1b[N1 + j], z = p1b[2 * N1 + j];
  float sk = __fadd_rn(__fadd_rn(__fmul_rn(x, x), __fmul_rn(y, y)),
                       __fmul_rn(z, z));
  return make_float4(x, y, z, sk);
}

// Lexicographic (d, idx) insert == stable top-k semantics (ties -> lower idx).
#define LEXINS(da, db, dc, ia, ib, ic, dd, jj)                                 \
  {                                                                            \
    bool ca = ((dd) < (da)) || ((dd) == (da) && (jj) < (ia));                  \
    bool cb = ((dd) < (db)) || ((dd) == (db) && (jj) < (ib));                  \
    bool cc = ((dd) < (dc)) || ((dd) == (dc) && (jj) < (ic));                  \
    dc = cb ? (db) : (cc ? (dd) : (dc));                                       \
    ic = cb ? (ib) : (cc ? (jj) : (ic));                                       \
    db = ca ? (da) : (cb ? (dd) : (db));                                       \
    ib = ca ? (ia) : (cb ? (jj) : (ib));                                       \
    da = ca ? (dd) : (da);                                                     \
    ia = ca ? (jj) : (ia);                                                     \
  }

// Sorted top-4 maintain on float keys: 1 min + 3 med3.
#define KMIN4(K1_, K2_, K3_, K4_, x)                                           \
  {                                                                            \
    float n1 = fminf((K1_), (x));                                              \
    float n2 = __builtin_amdgcn_fmed3f((K1_), (x), (K2_));                     \
    float n3 = __builtin_amdgcn_fmed3f((K2_), (x), (K3_));                     \
    float n4 = __builtin_amdgcn_fmed3f((K3_), (x), (K4_));                     \
    K1_ = n1; K2_ = n2; K3_ = n3; K4_ = n4;                                    \
  }

// Per-point scalar distance + key + keyed insert (key low 12 bits = index).
#define POINTQ(ux, uy, uz, su, px, py, pz, pw, jj, Ka, Kb, Kc, Kd)             \
  {                                                                            \
    float dot_ = __fadd_rn(                                                    \
        __fadd_rn(__fmul_rn((ux), (px)), __fmul_rn((uy), (py))),               \
        __fmul_rn((uz), (pz)));                                                \
    float dd_ = __builtin_fmaf(dot_, -2.0f, __fadd_rn((su), (pw)));            \
    float xk_ = __uint_as_float((__float_as_uint(dd_) & 0xFFFFF000u) |         \
                                ((unsigned)(jj) & 0x00000FFFu));               \
    KMIN4(Ka, Kb, Kc, Kd, xk_);                                                \
  }

// ---------------------------------------------------------------------------
// k_front: one kernel, three independent block ranges. NN blocks dispatch
// FIRST (they are the ~50us long pole); the ~11us of light prep/transpose
// work backfills spare issue slots (r16-proven co-residency overlap):
//   [0,512):    keyed 3-NN partials, points staged from p1 (exact RN |k|^2).
//   [512,896):  W1/W2 -> bf16; BN folded scale/shift.
//   [896,1408): transpose features1 [B,C1,N1] -> f1Tb [B,N1,C1] in BF16.
// ---------------------------------------------------------------------------
__global__ __launch_bounds__(256) void k_front(
    const float* __restrict__ p1, const float* __restrict__ p2,
    const float* __restrict__ f1,
    const float* __restrict__ W1, const float* __restrict__ W2,
    const float* __restrict__ b1, const float* __restrict__ g1,
    const float* __restrict__ be1, const float* __restrict__ mm1,
    const float* __restrict__ vv1,
    const float* __restrict__ b2, const float* __restrict__ g2,
    const float* __restrict__ be2, const float* __restrict__ mm2,
    const float* __restrict__ vv2,
    __bf16* __restrict__ W1b, __bf16* __restrict__ W2b,
    float* __restrict__ scsh, __bf16* __restrict__ f1Tb,
    float* __restrict__ keybuf) {
#pragma clang fp contract(off)
  __shared__ __align__(16) float smemf[64 * 65];   // 16,640B: spts / tile
  const int bx = blockIdx.x;
  const int t = threadIdx.x;

  if (bx < 512) {
    // ---- NN scan ----
    float4* spts = (float4*)smemf;        // 8KB used
    const int ch = bx & (NCH - 1);
    const int qt = bx >> 3;               // 0..63 (tiles of 512 queries)
    const int b  = qt >> 5;               // uniform per block
    const int nA = ((qt & 31) << 9) + t;  // query A
    const int nB = nA + 256;              // query B

    const float* p1b = p1 + (size_t)b * 3 * N1;
    {
      int j = ch * 512 + t;
      spts[t]       = load_pt(p1b, j);
      spts[t + 256] = load_pt(p1b, j + 256);
    }

    const float* p2b = p2 + (size_t)b * 3 * N2;
    float uxA = p2b[nA], uyA = p2b[N2 + nA], uzA = p2b[2 * N2 + nA];
    float suA = __fadd_rn(__fadd_rn(__fmul_rn(uxA, uxA), __fmul_rn(uyA, uyA)),
                          __fmul_rn(uzA, uzA));
    float uxB = p2b[nB], uyB = p2b[N2 + nB], uzB = p2b[2 * N2 + nB];
    float suB = __fadd_rn(__fadd_rn(__fmul_rn(uxB, uxB), __fmul_rn(uyB, uyB)),
                          __fmul_rn(uzB, uzB));
    __syncthreads();

    const int j0 = ch * 512;
    float KaA = 3.0e38f, KbA = 3.0e38f, KcA = 3.0e38f, KdA = 3.0e38f;
    float KaB = 3.0e38f, KbB = 3.0e38f, KcB = 3.0e38f, KdB = 3.0e38f;
#pragma unroll 4
    for (int k = 0; k < 256; ++k) {
      float4 p0 = spts[2 * k];
      float4 p1v = spts[2 * k + 1];
      int i0 = j0 + 2 * k;
      int i1 = j0 + 2 * k + 1;
      POINTQ(uxA, uyA, uzA, suA, p0.x, p0.y, p0.z, p0.w, i0,
             KaA, KbA, KcA, KdA);
      POINTQ(uxA, uyA, uzA, suA, p1v.x, p1v.y, p1v.z, p1v.w, i1,
             KaA, KbA, KcA, KdA);
      POINTQ(uxB, uyB, uzB, suB, p0.x, p0.y, p0.z, p0.w, i0,
             KaB, KbB, KcB, KdB);
      POINTQ(uxB, uyB, uzB, suB, p1v.x, p1v.y, p1v.z, p1v.w, i1,
             KaB, KbB, KcB, KdB);
    }

    int qA = b * N2 + nA;
    int qB = b * N2 + nB;
    keybuf[(ch * 4 + 0) * BQ + qA] = KaA;
    keybuf[(ch * 4 + 1) * BQ + qA] = KbA;
    keybuf[(ch * 4 + 2) * BQ + qA] = KcA;
    keybuf[(ch * 4 + 3) * BQ + qA] = KdA;
    keybuf[(ch * 4 + 0) * BQ + qB] = KaB;
    keybuf[(ch * 4 + 1) * BQ + qB] = KbB;
    keybuf[(ch * 4 + 2) * BQ + qB] = KcB;
    keybuf[(ch * 4 + 3) * BQ + qB] = KdB;
    return;
  }

  if (bx < 896) {
    // ---- prep: W -> bf16, BN fold ----
    int idx = (bx - 512) * 256 + t;
    if (idx < HH * K1) W1b[idx] = (__bf16)W1[idx];
    if (idx < HH * HH) W2b[idx] = (__bf16)W2[idx];
    if (idx < HH) {
      float sc = g1[idx] / sqrtf(vv1[idx] + 1e-3f);
      scsh[idx]          = sc;
      scsh[HH + idx]     = fmaf(b1[idx] - mm1[idx], sc, be1[idx]);
      float s2 = g2[idx] / sqrtf(vv2[idx] + 1e-3f);
      scsh[2 * HH + idx] = s2;
      scsh[3 * HH + idx] = fmaf(b2[idx] - mm2[idx], s2, be2[idx]);
    }
    return;
  }

  // ---- transpose: f1 -> f1Tb (bf16) ----
  {
    float (*tile)[65] = (float(*)[65])smemf;
    const int bz = bx - 896;            // 0..511
    const int b = bz >> 8;
    const int rest = bz & 255;
    const int ct = rest >> 6;
    const int ntb = (rest & 63) << 6;
    const int ln = t & 63, g = t >> 6;

    const float* src = f1 + ((size_t)b * C1 + ct * 64) * N1 + ntb;
    for (int k = 0; k < 16; ++k) {
      int c = (k << 2) + g;
      tile[c][ln] = src[(size_t)c * N1 + ln];
    }
    __syncthreads();
    __bf16* dst = f1Tb + ((size_t)b * N1 + ntb) * C1 + ct * 64;
    for (int k = 0; k < 16; ++k) {
      int nn = (k << 2) + g;
      dst[(size_t)nn * C1 + ln] = (__bf16)tile[ln][nn];
    }
  }
}

// ---------------------------------------------------------------------------
// k_fused: A2 (f2->LDS, independent) FIRST so its 16 strided loads fly under
// Phase A0's dependent keybuf-fold chain; then A0 in-register merge (cheap
// candidate-only fallback — r13/14/17's full-rescan was the catastrophe);
// then A1 bf16-row gather+interp; sync; MFMA GEMM1 -> BN1+ReLU -> MFMA
// GEMM2 -> BN2+ReLU -> out. Numerics byte-identical to the passing r20.
// ---------------------------------------------------------------------------
__global__ __launch_bounds__(512) void k_fused(
    const __bf16* __restrict__ f1Tb, const float* __restrict__ f2,
    const float* __restrict__ p2, const float* __restrict__ p1,
    const float* __restrict__ keybuf,
    const __bf16* __restrict__ W1b, const __bf16* __restrict__ W2b,
    const float* __restrict__ scsh, float* __restrict__ out) {
  __shared__ __bf16 sX[64 * KPAD];       // 49KB; x for GEMM1, then h
  const int t = threadIdx.x;
  const int bx = blockIdx.x;
  const int b = bx >> 8;
  const int n0 = (bx & 255) << 6;

  // ---- Phase A2 (hoisted): features2 channels (k = 256..383) ----
  {
    const int col = t & 63, g = t >> 6;
    const float* f2b = f2 + (size_t)b * C2 * N2 + n0 + col;
#pragma unroll
    for (int m = 0; m < 4; ++m) {
      int c4 = (g << 4) + (m << 2);
      bf16x4 v;
      v[0] = (__bf16)f2b[(size_t)(c4 + 0) * N2];
      v[1] = (__bf16)f2b[(size_t)(c4 + 1) * N2];
      v[2] = (__bf16)f2b[(size_t)(c4 + 2) * N2];
      v[3] = (__bf16)f2b[(size_t)(c4 + 3) * N2];
      *(bf16x4*)&sX[col * KPAD + 256 + c4] = v;
    }
  }

  // ---- Phase A0: in-register 3-NN merge + weights (8 lanes per query) ----
  float w0, w1, w2;
  int i0, i1, i2;
  {
#pragma clang fp contract(off)
    const int sub = t & 7;
    const int n = n0 + (t >> 3);
    const int gi = b * N2 + n;
    const float* p2b = p2 + (size_t)b * 3 * N2;
    float ux = p2b[n], uy = p2b[N2 + n], uz = p2b[2 * N2 + n];
    float su = __fadd_rn(__fadd_rn(__fmul_rn(ux, ux), __fmul_rn(uy, uy)),
                         __fmul_rn(uz, uz));

    float Ka = 3.0e38f, Kb = 3.0e38f, Kc = 3.0e38f, Kd = 3.0e38f;
#pragma unroll
    for (int m = 0; m < 4; ++m) {
      float x = keybuf[(sub * 4 + m) * BQ + gi];
      KMIN4(Ka, Kb, Kc, Kd, x);
    }
#pragma unroll
    for (int msk = 1; msk <= 4; msk <<= 1) {
      float ea = __shfl_xor(Ka, msk, 64), eb = __shfl_xor(Kb, msk, 64);
      float ec = __shfl_xor(Kc, msk, 64), ed = __shfl_xor(Kd, msk, 64);
      KMIN4(Ka, Kb, Kc, Kd, ea);
      KMIN4(Ka, Kb, Kc, Kd, eb);
      KMIN4(Ka, Kb, Kc, Kd, ec);
      KMIN4(Ka, Kb, Kc, Kd, ed);
    }
    bool flag = (__float_as_uint(Kc) >> 12) == (__float_as_uint(Kd) >> 12);

    const float* p1b = p1 + (size_t)b * 3 * N1;
    float da, db, dc;
    int ia, ib, ic;
    if (!flag) {
      ia = (int)(__float_as_uint(Ka) & 0xFFFu);
      ib = (int)(__float_as_uint(Kb) & 0xFFFu);
      ic = (int)(__float_as_uint(Kc) & 0xFFFu);
      da = exact_dd(ux, uy, uz, su, load_pt(p1b, ia));
      db = exact_dd(ux, uy, uz, su, load_pt(p1b, ib));
      dc = exact_dd(ux, uy, uz, su, load_pt(p1b, ic));
    } else {
      // cheap fallback: exact (d,idx) LEXINS over the 32 candidate keys
      da = 3.0e38f; db = 3.0e38f; dc = 3.0e38f;
      ia = 0x7fffffff; ib = 0x7fffffff; ic = 0x7fffffff;
#pragma unroll 4
      for (int i = 0; i < 4 * NCH; ++i) {
        float x = keybuf[i * BQ + gi];
        int jj = (int)(__float_as_uint(x) & 0xFFFu);
        float dd = exact_dd(ux, uy, uz, su, load_pt(p1b, jj));
        LEXINS(da, db, dc, ia, ib, ic, dd, jj);
      }
    }

    // exact reference weight arithmetic (all 8 lanes identically)
    float qa = fmaxf(da, 0.0f), qb = fmaxf(db, 0.0f), qc = fmaxf(dc, 0.0f);
    qa = fmaxf(__fmul_rn(qa, qa), 1e-10f);
    qb = fmaxf(__fmul_rn(qb, qb), 1e-10f);
    qc = fmaxf(__fmul_rn(qc, qc), 1e-10f);
    float va = __fdiv_rn(1.0f, qa);
    float vb = __fdiv_rn(1.0f, qb);
    float vc = __fdiv_rn(1.0f, qc);
    float s = __fadd_rn(__fadd_rn(va, vb), vc);
    w0 = __fdiv_rn(va, s);
    w1 = __fdiv_rn(vb, s);
    w2 = __fdiv_rn(vc, s);
    i0 = ia; i1 = ib; i2 = ic;
  }

  // ---- Phase A1: interp C1 channels from bf16 rows; 8 thr/col x 4 chunks --
  {
    const int qq = t & 7;
    const __bf16* r0 = f1Tb + ((size_t)b * N1 + i0) * C1;
    const __bf16* r1 = f1Tb + ((size_t)b * N1 + i1) * C1;
    const __bf16* r2 = f1Tb + ((size_t)b * N1 + i2) * C1;
#pragma unroll
    for (int m = 0; m < 4; ++m) {
      int c8 = ((qq << 2) + m) << 3;     // element base 0..248
      bf16x8 a = *(const bf16x8*)(r0 + c8);
      bf16x8 c4 = *(const bf16x8*)(r1 + c8);
      bf16x8 d4 = *(const bf16x8*)(r2 + c8);
      bf16x8 v;
#pragma unroll
      for (int e = 0; e < 8; ++e)
        v[e] = (__bf16)fmaf(w0, (float)a[e],
                            fmaf(w1, (float)c4[e], w2 * (float)d4[e]));
      *(bf16x8*)&sX[(t >> 3) * KPAD + c8] = v;
    }
  }
  __syncthreads();

  const int l  = t & 63;
  const int wv = __builtin_amdgcn_readfirstlane(t >> 6);
  const int ob = wv << 5;                // 32 rows per wave
  const int lm = l & 15, lg = l >> 4;

  f32x4 acc[2][4];
#pragma unroll
  for (int mt = 0; mt < 2; ++mt)
#pragma unroll
    for (int nt = 0; nt < 4; ++nt) acc[mt][nt] = (f32x4)0.0f;

  // ---- GEMM1: K = 384 (12 k-steps) ----
  for (int ks = 0; ks < 12; ++ks) {
    bf16x8 af[2], bfr[4];
#pragma unroll
    for (int mt = 0; mt < 2; ++mt)
      af[mt] = *(const bf16x8*)(W1b + (size_t)(ob + mt * 16 + lm) * K1 +
                                ks * 32 + lg * 8);
#pragma unroll
    for (int nt = 0; nt < 4; ++nt)
      bfr[nt] = *(const bf16x8*)&sX[(nt * 16 + lm) * KPAD + ks * 32 + lg * 8];
#pragma unroll
    for (int mt = 0; mt < 2; ++mt)
#pragma unroll
      for (int nt = 0; nt < 4; ++nt)
        acc[mt][nt] = __builtin_amdgcn_mfma_f32_16x16x32_bf16(
            af[mt], bfr[nt], acc[mt][nt], 0, 0, 0);
  }
  __syncthreads();

  // ---- BN1 + ReLU -> h (bf16) back into sX ----
#pragma unroll
  for (int mt = 0; mt < 2; ++mt) {
    int rb = ob + mt * 16 + lg * 4;
    float4 sc4 = *(const float4*)(scsh + rb);
    float4 sh4 = *(const float4*)(scsh + HH + rb);
#pragma unroll
    for (int nt = 0; nt < 4; ++nt) {
      int colc = nt * 16 + lm;
      bf16x4 v;
      v[0] = (__bf16)fmaxf(fmaf(acc[mt][nt][0], sc4.x, sh4.x), 0.0f);
      v[1] = (__bf16)fmaxf(fmaf(acc[mt][nt][1], sc4.y, sh4.y), 0.0f);
      v[2] = (__bf16)fmaxf(fmaf(acc[mt][nt][2], sc4.z, sh4.z), 0.0f);
      v[3] = (__bf16)fmaxf(fmaf(acc[mt][nt][3], sc4.w, sh4.w), 0.0f);
      *(bf16x4*)&sX[colc * KPAD + rb] = v;
    }
  }
  __syncthreads();

  // ---- GEMM2: K = 256 (8 k-steps) ----
  f32x4 ac2[2][4];
#pragma unroll
  for (int mt = 0; mt < 2; ++mt)
#pragma unroll
    for (int nt = 0; nt < 4; ++nt) ac2[mt][nt] = (f32x4)0.0f;
  for (int ks = 0; ks < 8; ++ks) {
    bf16x8 af[2], bfr[4];
#pragma unroll
    for (int mt = 0; mt < 2; ++mt)
      af[mt] = *(const bf16x8*)(W2b + (size_t)(ob + mt * 16 + lm) * HH +
                                ks * 32 + lg * 8);
#pragma unroll
    for (int nt = 0; nt < 4; ++nt)
      bfr[nt] = *(const bf16x8*)&sX[(nt * 16 + lm) * KPAD + ks * 32 + lg * 8];
#pragma unroll
    for (int mt = 0; mt < 2; ++mt)
#pragma unroll
      for (int nt = 0; nt < 4; ++nt)
        ac2[mt][nt] = __builtin_amdgcn_mfma_f32_16x16x32_bf16(
            af[mt], bfr[nt], ac2[mt][nt], 0, 0, 0);
  }

  // ---- BN2 + ReLU -> out (fp32) ----
  float* outb = out + (size_t)b * HH * N2 + n0;
#pragma unroll
  for (int mt = 0; mt < 2; ++mt) {
    int rb = ob + mt * 16 + lg * 4;
    float4 sc4 = *(const float4*)(scsh + 2 * HH + rb);
    float4 sh4 = *(const float4*)(scsh + 3 * HH + rb);
#pragma unroll
    for (int nt = 0; nt < 4; ++nt) {
      int colc = nt * 16 + lm;
      outb[(size_t)(rb + 0) * N2 + colc] =
          fmaxf(fmaf(ac2[mt][nt][0], sc4.x, sh4.x), 0.0f);
      outb[(size_t)(rb + 1) * N2 + colc] =
          fmaxf(fmaf(ac2[mt][nt][1], sc4.y, sh4.y), 0.0f);
      outb[(size_t)(rb + 2) * N2 + colc] =
          fmaxf(fmaf(ac2[mt][nt][2], sc4.z, sh4.z), 0.0f);
      outb[(size_t)(rb + 3) * N2 + colc] =
          fmaxf(fmaf(ac2[mt][nt][3], sc4.w, sh4.w), 0.0f);
    }
  }
}

// ---------------------------------------------------------------------------
extern "C" void kernel_launch(void* const* d_in, const int* in_sizes, int n_in,
                              void* d_out, int out_size, void* d_ws, size_t ws_size,
                              hipStream_t stream) {
  const float* p1  = (const float*)d_in[0];
  const float* p2  = (const float*)d_in[1];
  const float* f1  = (const float*)d_in[2];
  const float* f2  = (const float*)d_in[3];
  const float* W1  = (const float*)d_in[4];
  const float* bb1 = (const float*)d_in[5];
  const float* g1  = (const float*)d_in[6];
  const float* be1 = (const float*)d_in[7];
  const float* mm1 = (const float*)d_in[8];
  const float* vv1 = (const float*)d_in[9];
  const float* W2  = (const float*)d_in[10];
  const float* bb2 = (const float*)d_in[11];
  const float* g2  = (const float*)d_in[12];
  const float* be2 = (const float*)d_in[13];
  const float* mm2 = (const float*)d_in[14];
  const float* vv2 = (const float*)d_in[15];
  float* out = (float*)d_out;

  // ws layout (~8.7 MB, no aliasing — f1Tb bf16 = 4MB).
  char* ws = (char*)d_ws;
  __bf16* f1Tb   = (__bf16*)(ws);                // 4,194,304 B
  float*  keybuf = (float*)(ws + 4194304);       // 4,194,304 B (32 planes)
  __bf16* W1b    = (__bf16*)(ws + 8388608);      //   196,608 B
  __bf16* W2b    = (__bf16*)(ws + 8585216);      //   131,072 B
  float*  scsh   = (float*)(ws + 8716288);       //     4,096 B

  k_front<<<1408, 256, 0, stream>>>(p1, p2, f1, W1, W2,
                                    bb1, g1, be1, mm1, vv1,
                                    bb2, g2, be2, mm2, vv2,
                                    W1b, W2b, scsh, f1Tb, keybuf);
  k_fused<<<512, 512, 0, stream>>>(f1Tb, f2, p2, p1, keybuf,
                                   W1b, W2b, scsh, out);
}